// Round 1
// baseline (2374.086 us; speedup 1.0000x reference)
//
#include <hip/hip_runtime.h>
#include <math.h>

// Problem constants
constexpr int kBS   = 16;
constexpr int kL    = 50;
constexpr int kNB   = 64;
constexpr int kD    = 256;
constexpr int kNBLK = 65536;

#define NEG_HUGE (-3.402823466e38f)

// ---------------- helpers ----------------
__device__ __forceinline__ unsigned f2sort(float f) {
    unsigned u = __float_as_uint(f);
    return (u & 0x80000000u) ? ~u : (u | 0x80000000u);   // monotone ascending map
}

// bitonic ascending sort of n u64 keys in LDS, blockDim.x == n (power of 2)
__device__ __forceinline__ void bitonic_u64(unsigned long long* s, int i, int n) {
    for (int k = 2; k <= n; k <<= 1) {
        for (int j = k >> 1; j > 0; j >>= 1) {
            __syncthreads();
            int ixj = i ^ j;
            if (ixj > i) {
                unsigned long long x = s[i], y = s[ixj];
                bool sw = ((i & k) == 0) ? (x > y) : (x < y);
                if (sw) { s[i] = y; s[ixj] = x; }
            }
        }
    }
    __syncthreads();
}

// ---------------- generic f32 GEMM: C[M,N] = op(Asrc @ B + bias) ----------------
// A row r comes from A[(gather? gather[r] : abase+r) * lda]. BM=BN=128, BK=8.
// Requires N % 128 == 0, K % 8 == 0, lda/ldb % 4 == 0. M bounds-checked.
__global__ __launch_bounds__(256) void gemm128_f32(
    const float* __restrict__ A, int lda, const int* __restrict__ gather, int abase,
    const float* __restrict__ B, int ldb,
    float* __restrict__ C, int ldc,
    int M, int N, int K,
    const float* __restrict__ bias, int relu)
{
    __shared__ float As[8][128];
    __shared__ float Bs[8][132];
    const int t  = threadIdx.x;
    const int tx = t & 15, ty = t >> 4;
    const int bm = blockIdx.x * 128;
    const int bn = blockIdx.y * 128;

    const int mA   = t >> 1;
    const int kA   = (t & 1) * 4;
    const int rowA = bm + mA;
    const bool rowok = rowA < M;
    long long srcrow = 0;
    if (rowok) srcrow = gather ? (long long)gather[rowA] : (long long)(abase + rowA);
    const float* aptr = A + srcrow * (long long)lda + kA;

    const int kB = t >> 5;
    const int nB = (t & 31) * 4;
    const float* bptr = B + (long long)kB * ldb + bn + nB;

    float acc[8][8];
    #pragma unroll
    for (int i = 0; i < 8; ++i)
        #pragma unroll
        for (int j = 0; j < 8; ++j) acc[i][j] = 0.f;

    for (int k0 = 0; k0 < K; k0 += 8) {
        float4 av = make_float4(0.f, 0.f, 0.f, 0.f);
        if (rowok) av = *(const float4*)(aptr + k0);
        float4 bv = *(const float4*)(bptr + (long long)k0 * ldb);
        __syncthreads();
        As[kA + 0][mA] = av.x;
        As[kA + 1][mA] = av.y;
        As[kA + 2][mA] = av.z;
        As[kA + 3][mA] = av.w;
        *(float4*)&Bs[kB][nB] = bv;
        __syncthreads();
        #pragma unroll
        for (int k = 0; k < 8; ++k) {
            float a[8], b[8];
            *(float4*)&a[0] = *(const float4*)&As[k][ty * 8];
            *(float4*)&a[4] = *(const float4*)&As[k][ty * 8 + 4];
            *(float4*)&b[0] = *(const float4*)&Bs[k][tx * 8];
            *(float4*)&b[4] = *(const float4*)&Bs[k][tx * 8 + 4];
            #pragma unroll
            for (int i = 0; i < 8; ++i)
                #pragma unroll
                for (int j = 0; j < 8; ++j)
                    acc[i][j] = fmaf(a[i], b[j], acc[i][j]);
        }
    }
    #pragma unroll
    for (int i = 0; i < 8; ++i) {
        int row = bm + ty * 8 + i;
        if (row >= M) continue;
        #pragma unroll
        for (int j = 0; j < 8; ++j) {
            int col = bn + tx * 8 + j;
            float v = acc[i][j];
            if (bias) v += bias[col];
            if (relu) v = fmaxf(v, 0.f);
            C[(long long)row * ldc + col] = v;
        }
    }
}

// ---------------- in-place LayerNorm over rows of 256 ----------------
__global__ __launch_bounds__(256) void ln256_inplace(
    float* __restrict__ Y, const float* __restrict__ g, const float* __restrict__ b, int M)
{
    int row = blockIdx.x;
    if (row >= M) return;
    int d = threadIdx.x;
    float v = Y[(long long)row * 256 + d];
    __shared__ float red[256];
    red[d] = v; __syncthreads();
    for (int off = 128; off; off >>= 1) { if (d < off) red[d] += red[d + off]; __syncthreads(); }
    float mu = red[0] * (1.f / 256.f);
    __syncthreads();
    float dv = v - mu;
    red[d] = dv * dv; __syncthreads();
    for (int off = 128; off; off >>= 1) { if (d < off) red[d] += red[d + off]; __syncthreads(); }
    float var = red[0] * (1.f / 256.f);
    float out = g[d] * dv * (1.f / sqrtf(var + 1e-5f)) + b[d];
    Y[(long long)row * 256 + d] = out;
}

// ---------------- elementwise add ----------------
__global__ void add_vec(const float* __restrict__ a, const float* __restrict__ b,
                        float* __restrict__ c, int n)
{
    int i = blockIdx.x * 256 + threadIdx.x;
    if (i < n) c[i] = a[i] + b[i];
}

// ---------------- phase-1 scores: score = tanh(tvp + A[id]) . am_w2 ----------------
__global__ __launch_bounds__(256) void p1score(
    const float* __restrict__ tvp, const float* __restrict__ Atab,
    const float* __restrict__ am_w2, const int* __restrict__ ids,
    float* __restrict__ scores)
{
    int bl = blockIdx.x;            // 0..799 == (b*50+l)
    int lane = threadIdx.x & 63;
    int wv   = threadIdx.x >> 6;    // 0..3
    float4 tv = *(const float4*)(tvp + (long long)bl * 256 + lane * 4);
    float4 w2 = *(const float4*)(am_w2 + lane * 4);
    for (int s = wv * 16; s < wv * 16 + 16; ++s) {
        int id = ids[bl * 64 + s];
        float4 a = *(const float4*)(Atab + (long long)id * 256 + lane * 4);
        double p = (double)tanhf(tv.x + a.x) * w2.x
                 + (double)tanhf(tv.y + a.y) * w2.y
                 + (double)tanhf(tv.z + a.z) * w2.z
                 + (double)tanhf(tv.w + a.w) * w2.w;
        #pragma unroll
        for (int off = 32; off; off >>= 1) p += __shfl_down(p, off);
        if (lane == 0) scores[bl * 64 + s] = (float)p;
    }
}

// ---------------- phase-1 full sort (top-64 of 64, stable desc) ----------------
__global__ __launch_bounds__(64) void p1sort(
    const float* __restrict__ scores, const int* __restrict__ ids_in,
    const int* __restrict__ mk_in, int* __restrict__ sel_ids, int* __restrict__ sel_mk)
{
    int bl = blockIdx.x;
    int i = threadIdx.x;
    __shared__ unsigned long long s[64];
    float sc = scores[bl * 64 + i];
    int mk = mk_in[bl * 64 + i];
    float key = mk ? sc : NEG_HUGE;   // masked -> after all unmasked; ties by index
    s[i] = ((unsigned long long)(~f2sort(key)) << 32) | (unsigned)i;
    bitonic_u64(s, i, 64);
    int src = (int)(unsigned)(s[i] & 0xffffffffull);
    sel_ids[bl * 64 + i] = ids_in[bl * 64 + src];
    sel_mk [bl * 64 + i] = mk_in [bl * 64 + src];
}

// ---------------- E table: E[b,t,l*64+s] = qw[b,t+1] . K[sel_ids[b,l,s]] ----------------
__global__ __launch_bounds__(256) void etab(
    const float* __restrict__ qw, const float* __restrict__ Ktab,
    const int* __restrict__ sel_ids, float* __restrict__ E)
{
    int l = blockIdx.x;   // 0..49
    int b = blockIdx.y;   // 0..15
    __shared__ float Kl[64][256];    // 64 KiB
    int t = threadIdx.x;
    for (int base = 0; base < 64 * 256; base += 256 * 4) {
        int idx = base + t * 4;
        int r = idx >> 8, c = idx & 255;
        int id = sel_ids[(b * kL + l) * 64 + r];
        *(float4*)&Kl[r][c] = *(const float4*)(Ktab + (long long)id * 256 + c);
    }
    __syncthreads();
    int lane = t & 63, wv = t >> 6;
    for (int ts = 0; ts < 49; ++ts) {
        float4 q = *(const float4*)(qw + (long long)(b * kL + ts + 1) * 256 + lane * 4);
        for (int s = wv * 16; s < wv * 16 + 16; ++s) {
            float4 kv = *(const float4*)&Kl[s][lane * 4];
            double p = (double)q.x * kv.x + (double)q.y * kv.y
                     + (double)q.z * kv.z + (double)q.w * kv.w;
            #pragma unroll
            for (int off = 32; off; off >>= 1) p += __shfl_down(p, off);
            if (lane == 0) E[((long long)b * 49 + ts) * 3200 + l * 64 + s] = (float)p;
        }
    }
}

// ---------------- sequential memory recurrence (one block per batch) ----------------
__global__ __launch_bounds__(128) void recur(
    const float* __restrict__ E, const int* __restrict__ sel_ids,
    const int* __restrict__ sel_mk, const int* __restrict__ lengths,
    int* __restrict__ memf, float* __restrict__ dout_mem)
{
    int b = blockIdx.x;
    int t = threadIdx.x;
    __shared__ int cid[64], cmk[64], ccd[64];
    __shared__ int fid[128], fmk[128], fcd[128];
    __shared__ unsigned long long sk[128];
    if (t < 64) {
        cid[t] = sel_ids[(b * kL) * 64 + t];
        cmk[t] = sel_mk [(b * kL) * 64 + t];
        ccd[t] = t;                       // candidate index of visit 0
    }
    __syncthreads();
    int tlast = lengths[b] - 2;           // in [0,48]
    for (int ts = 0; ts <= tlast; ++ts) {
        int id, mk, cd;
        if (t < 64) { id = cid[t]; mk = cmk[t]; cd = ccd[t]; }
        else {
            int j = t - 64;
            id = sel_ids[(b * kL + ts + 1) * 64 + j];
            mk = sel_mk [(b * kL + ts + 1) * 64 + j];
            cd = (ts + 1) * 64 + j;
        }
        float key = mk ? E[((long long)b * 49 + ts) * 3200 + cd] : NEG_HUGE;
        fid[t] = id; fmk[t] = mk; fcd[t] = cd;
        sk[t] = ((unsigned long long)(~f2sort(key)) << 32) | (unsigned)t;
        bitonic_u64(sk, t, 128);
        if (t < 64) {
            int src = (int)(unsigned)(sk[t] & 0xffffffffull);
            cid[t] = fid[src]; cmk[t] = fmk[src]; ccd[t] = fcd[src];
        }
        __syncthreads();
    }
    if (t < 64) {
        int v = cid[t];
        memf[b * 64 + t] = v;
        dout_mem[b * 64 + t] = (float)v;  // output 1 (ids as f32)
    }
}

// ---------------- final pooling + output head ----------------
__global__ __launch_bounds__(256) void head_k(
    const float* __restrict__ tva, const int* __restrict__ lengths,
    const float* __restrict__ Tmem, const float* __restrict__ out_w,
    const float* __restrict__ out_b, float* __restrict__ dout)
{
    int b = blockIdx.x, d = threadIdx.x;
    int len = lengths[b];
    float vf = NEG_HUGE;
    for (int l = 0; l < len; ++l) vf = fmaxf(vf, tva[((long long)b * kL + l) * 256 + d]);
    float mv = NEG_HUGE;
    for (int m = 0; m < 64; ++m) mv = fmaxf(mv, Tmem[((long long)b * 64 + m) * 256 + d]);
    double p0 = (double)vf * out_w[d * 2 + 0] + (double)mv * out_w[(256 + d) * 2 + 0];
    double p1 = (double)vf * out_w[d * 2 + 1] + (double)mv * out_w[(256 + d) * 2 + 1];
    __shared__ double r0[256], r1[256];
    r0[d] = p0; r1[d] = p1; __syncthreads();
    for (int off = 128; off; off >>= 1) {
        if (d < off) { r0[d] += r0[d + off]; r1[d] += r1[d + off]; }
        __syncthreads();
    }
    if (d == 0) {
        dout[b * 2 + 0] = (float)(r0[0] + out_b[0]);
        dout[b * 2 + 1] = (float)(r1[0] + out_b[1]);
    }
}

// ---------------- host orchestration ----------------
extern "C" void kernel_launch(void* const* d_in, const int* in_sizes, int n_in,
                              void* d_out, int out_size, void* d_ws, size_t ws_size,
                              hipStream_t stream)
{
    const float* v_all  = (const float*)d_in[0];
    const float* tva    = (const float*)d_in[1];
    const float* emb    = (const float*)d_in[2];
    const float* bt_w1  = (const float*)d_in[3];
    const float* bt_b1  = (const float*)d_in[4];
    const float* bt_w2  = (const float*)d_in[5];
    const float* bt_b2  = (const float*)d_in[6];
    const float* bt_g   = (const float*)d_in[7];
    const float* bt_bb  = (const float*)d_in[8];
    const float* wq     = (const float*)d_in[9];
    const float* wk     = (const float*)d_in[10];
    const float* am_w1  = (const float*)d_in[11];
    const float* am_b1  = (const float*)d_in[12];
    const float* am_w2  = (const float*)d_in[13];
    const float* out_w  = (const float*)d_in[14];
    const float* out_b  = (const float*)d_in[15];
    const int*   in_txt = (const int*)d_in[16];
    const int*   mk_txt = (const int*)d_in[17];
    const int*   lens   = (const int*)d_in[18];
    float* dout = (float*)d_out;

    // ---- workspace layout (floats) ----
    const size_t FT_TAB = (size_t)kNBLK * 256;          // 16.78M each
    const size_t FT_E   = (size_t)16 * 49 * 3200;       // 2.51M
    const size_t FT_SM  = (size_t)800 * 256 * 3 + (size_t)800 * 64 * 3 + 1024 + 64;
    int CH = 32768;
    for (;;) {
        size_t yrows = (size_t)(CH > 1024 ? CH : 1024);
        size_t need = FT_TAB * 2 + FT_E + (size_t)CH * 512 + yrows * 256 + FT_SM + 64;
        if (need * 4 <= ws_size || CH == 1024) break;
        CH >>= 1;
    }
    size_t off = 0;
    float* W = (float*)d_ws;
    auto take = [&](size_t n) { float* p = W + off; off += (n + 3) & ~(size_t)3; return p; };
    float* Atab = take(FT_TAB);
    float* Ktab = take(FT_TAB);
    float* Ep   = take(FT_E);
    float* Hp   = take((size_t)CH * 512);
    float* Yp   = take((size_t)(CH > 1024 ? CH : 1024) * 256);
    float* qrP  = take((size_t)800 * 256);
    float* tvpP = take((size_t)800 * 256);
    float* qwP  = take((size_t)800 * 256);
    float* scP  = take((size_t)800 * 64);
    int*   selI = (int*)take((size_t)800 * 64);
    int*   selM = (int*)take((size_t)800 * 64);
    int*   memfP = (int*)take(1024);

    // 1) query = transformed_v_all + v_all
    add_vec<<<dim3((204800 + 255) / 256), dim3(256), 0, stream>>>(v_all, tva, qrP, 204800);

    // 2) tvp = tva @ am_w1[:256] + am_b1 ; qw = query @ wq
    gemm128_f32<<<dim3(7, 2), dim3(256), 0, stream>>>(
        tva, 256, nullptr, 0, am_w1, 256, tvpP, 256, 800, 256, 256, am_b1, 0);
    gemm128_f32<<<dim3(7, 2), dim3(256), 0, stream>>>(
        qrP, 256, nullptr, 0, wq, 256, qwP, 256, 800, 256, 256, nullptr, 0);

    // 3) per-ID tables in chunks: T (via H,Y), then A = T@am_w1[256:], K = T@wk
    int nch = kNBLK / CH;
    for (int c = 0; c < nch; ++c) {
        gemm128_f32<<<dim3(CH / 128, 4), dim3(256), 0, stream>>>(
            emb, 768, nullptr, c * CH, bt_w1, 512, Hp, 512, CH, 512, 768, bt_b1, 1);
        gemm128_f32<<<dim3(CH / 128, 2), dim3(256), 0, stream>>>(
            Hp, 512, nullptr, 0, bt_w2, 256, Yp, 256, CH, 256, 512, bt_b2, 0);
        ln256_inplace<<<dim3(CH), dim3(256), 0, stream>>>(Yp, bt_g, bt_bb, CH);
        gemm128_f32<<<dim3(CH / 128, 2), dim3(256), 0, stream>>>(
            Yp, 256, nullptr, 0, am_w1 + 256 * 256, 256, Atab + (size_t)c * CH * 256,
            256, CH, 256, 256, nullptr, 0);
        gemm128_f32<<<dim3(CH / 128, 2), dim3(256), 0, stream>>>(
            Yp, 256, nullptr, 0, wk, 256, Ktab + (size_t)c * CH * 256,
            256, CH, 256, 256, nullptr, 0);
    }

    // 4) phase-1 scores + stable full sort -> sel_ids / sel_mask
    p1score<<<dim3(800), dim3(256), 0, stream>>>(tvpP, Atab, am_w2, in_txt, scP);
    p1sort<<<dim3(800), dim3(64), 0, stream>>>(scP, in_txt, mk_txt, selI, selM);

    // 5) E table for all (b, t, candidate)
    etab<<<dim3(50, 16), dim3(256), 0, stream>>>(qwP, Ktab, selI, Ep);

    // 6) sequential recurrence -> memory_final (writes output 1)
    recur<<<dim3(16), dim3(128), 0, stream>>>(Ep, selI, selM, lens, memfP, dout + 32);

    // 7) transform memory_final ids -> Tmem (reuse Hp/Yp)
    gemm128_f32<<<dim3(8, 4), dim3(256), 0, stream>>>(
        emb, 768, memfP, 0, bt_w1, 512, Hp, 512, 1024, 512, 768, bt_b1, 1);
    gemm128_f32<<<dim3(8, 2), dim3(256), 0, stream>>>(
        Hp, 512, nullptr, 0, bt_w2, 256, Yp, 256, 1024, 256, 512, bt_b2, 0);
    ln256_inplace<<<dim3(1024), dim3(256), 0, stream>>>(Yp, bt_g, bt_bb, 1024);

    // 8) pooling + output head (writes output 0)
    head_k<<<dim3(16), dim3(256), 0, stream>>>(tva, lens, Yp, out_w, out_b, dout);
}

// Round 2
// 1816.335 us; speedup vs baseline: 1.3071x; 1.3071x over previous
//
#include <hip/hip_runtime.h>
#include <math.h>

// Problem constants
constexpr int kBS   = 16;
constexpr int kL    = 50;
constexpr int kNB   = 64;
constexpr int kD    = 256;
constexpr int kNBLK = 65536;

#define NEG_HUGE (-3.402823466e38f)

// ---------------- helpers ----------------
__device__ __forceinline__ unsigned f2sort(float f) {
    unsigned u = __float_as_uint(f);
    return (u & 0x80000000u) ? ~u : (u | 0x80000000u);   // monotone ascending map
}

// bitonic ascending sort of n u64 keys in LDS, blockDim.x == n (power of 2)
__device__ __forceinline__ void bitonic_u64(unsigned long long* s, int i, int n) {
    for (int k = 2; k <= n; k <<= 1) {
        for (int j = k >> 1; j > 0; j >>= 1) {
            __syncthreads();
            int ixj = i ^ j;
            if (ixj > i) {
                unsigned long long x = s[i], y = s[ixj];
                bool sw = ((i & k) == 0) ? (x > y) : (x < y);
                if (sw) { s[i] = y; s[ixj] = x; }
            }
        }
    }
    __syncthreads();
}

// ---------------- generic f32 GEMM: C[M,N] = op(Asrc @ B + bias) ----------------
// A row r comes from A[(gather? gather[r] : abase+r) * lda]. BM=BN=128, BK=16.
// Requires N % 128 == 0, K % 16 == 0, lda/ldb % 4 == 0. M bounds-checked.
__global__ __launch_bounds__(256) void gemm128_f32(
    const float* __restrict__ A, int lda, const int* __restrict__ gather, int abase,
    const float* __restrict__ B, int ldb,
    float* __restrict__ C, int ldc,
    int M, int N, int K,
    const float* __restrict__ bias, int relu)
{
    __shared__ float As[16][128];
    __shared__ float Bs[16][132];
    const int t  = threadIdx.x;
    const int tx = t & 15, ty = t >> 4;
    const int bm = blockIdx.x * 128;
    const int bn = blockIdx.y * 128;

    const int mA   = t >> 1;          // 0..127
    const int kA   = (t & 1) * 8;     // 0 or 8
    const int rowA = bm + mA;
    const bool rowok = rowA < M;
    long long srcrow = 0;
    if (rowok) srcrow = gather ? (long long)gather[rowA] : (long long)(abase + rowA);
    const float* aptr = A + srcrow * (long long)lda + kA;

    const int kB = t >> 4;            // 0..15
    const int nB = (t & 15) * 8;      // 0..120
    const float* bptr = B + (long long)kB * ldb + bn + nB;

    float acc[8][8];
    #pragma unroll
    for (int i = 0; i < 8; ++i)
        #pragma unroll
        for (int j = 0; j < 8; ++j) acc[i][j] = 0.f;

    for (int k0 = 0; k0 < K; k0 += 16) {
        float4 a0 = make_float4(0.f, 0.f, 0.f, 0.f), a1 = a0;
        if (rowok) {
            a0 = *(const float4*)(aptr + k0);
            a1 = *(const float4*)(aptr + k0 + 4);
        }
        float4 b0 = *(const float4*)(bptr + (long long)k0 * ldb);
        float4 b1 = *(const float4*)(bptr + (long long)k0 * ldb + 4);
        __syncthreads();
        As[kA + 0][mA] = a0.x; As[kA + 1][mA] = a0.y;
        As[kA + 2][mA] = a0.z; As[kA + 3][mA] = a0.w;
        As[kA + 4][mA] = a1.x; As[kA + 5][mA] = a1.y;
        As[kA + 6][mA] = a1.z; As[kA + 7][mA] = a1.w;
        *(float4*)&Bs[kB][nB]     = b0;
        *(float4*)&Bs[kB][nB + 4] = b1;
        __syncthreads();
        #pragma unroll
        for (int k = 0; k < 16; ++k) {
            float a[8], b[8];
            *(float4*)&a[0] = *(const float4*)&As[k][ty * 8];
            *(float4*)&a[4] = *(const float4*)&As[k][ty * 8 + 4];
            *(float4*)&b[0] = *(const float4*)&Bs[k][tx * 8];
            *(float4*)&b[4] = *(const float4*)&Bs[k][tx * 8 + 4];
            #pragma unroll
            for (int i = 0; i < 8; ++i)
                #pragma unroll
                for (int j = 0; j < 8; ++j)
                    acc[i][j] = fmaf(a[i], b[j], acc[i][j]);
        }
    }
    #pragma unroll
    for (int i = 0; i < 8; ++i) {
        int row = bm + ty * 8 + i;
        if (row >= M) continue;
        #pragma unroll
        for (int j = 0; j < 8; ++j) {
            int col = bn + tx * 8 + j;
            float v = acc[i][j];
            if (bias) v += bias[col];
            if (relu) v = fmaxf(v, 0.f);
            C[(long long)row * ldc + col] = v;
        }
    }
}

// ---------------- in-place LayerNorm over rows of 256 ----------------
__global__ __launch_bounds__(256) void ln256_inplace(
    float* __restrict__ Y, const float* __restrict__ g, const float* __restrict__ b, int M)
{
    int row = blockIdx.x;
    if (row >= M) return;
    int d = threadIdx.x;
    float v = Y[(long long)row * 256 + d];
    __shared__ float red[256];
    red[d] = v; __syncthreads();
    for (int off = 128; off; off >>= 1) { if (d < off) red[d] += red[d + off]; __syncthreads(); }
    float mu = red[0] * (1.f / 256.f);
    __syncthreads();
    float dv = v - mu;
    red[d] = dv * dv; __syncthreads();
    for (int off = 128; off; off >>= 1) { if (d < off) red[d] += red[d + off]; __syncthreads(); }
    float var = red[0] * (1.f / 256.f);
    float out = g[d] * dv * (1.f / sqrtf(var + 1e-5f)) + b[d];
    Y[(long long)row * 256 + d] = out;
}

// ---------------- elementwise add ----------------
__global__ void add_vec(const float* __restrict__ a, const float* __restrict__ b,
                        float* __restrict__ c, int n)
{
    int i = blockIdx.x * 256 + threadIdx.x;
    if (i < n) c[i] = a[i] + b[i];
}

// ---------------- phase-1 scores: score = tanh(tvp + A[id]) . am_w2 ----------------
__global__ __launch_bounds__(256) void p1score(
    const float* __restrict__ tvp, const float* __restrict__ Atab,
    const float* __restrict__ am_w2, const int* __restrict__ ids,
    float* __restrict__ scores)
{
    int bl = blockIdx.x;            // 0..799 == (b*50+l)
    int lane = threadIdx.x & 63;
    int wv   = threadIdx.x >> 6;    // 0..3
    float4 tv = *(const float4*)(tvp + (long long)bl * 256 + lane * 4);
    float4 w2 = *(const float4*)(am_w2 + lane * 4);
    for (int s = wv * 16; s < wv * 16 + 16; ++s) {
        int id = ids[bl * 64 + s];
        float4 a = *(const float4*)(Atab + (long long)id * 256 + lane * 4);
        double p = (double)tanhf(tv.x + a.x) * w2.x
                 + (double)tanhf(tv.y + a.y) * w2.y
                 + (double)tanhf(tv.z + a.z) * w2.z
                 + (double)tanhf(tv.w + a.w) * w2.w;
        #pragma unroll
        for (int off = 32; off; off >>= 1) p += __shfl_down(p, off);
        if (lane == 0) scores[bl * 64 + s] = (float)p;
    }
}

// ---------------- phase-1 full sort (top-64 of 64, stable desc) ----------------
__global__ __launch_bounds__(64) void p1sort(
    const float* __restrict__ scores, const int* __restrict__ ids_in,
    const int* __restrict__ mk_in, int* __restrict__ sel_ids, int* __restrict__ sel_mk)
{
    int bl = blockIdx.x;
    int i = threadIdx.x;
    __shared__ unsigned long long s[64];
    float sc = scores[bl * 64 + i];
    int mk = mk_in[bl * 64 + i];
    float key = mk ? sc : NEG_HUGE;   // masked -> after all unmasked; ties by index
    s[i] = ((unsigned long long)(~f2sort(key)) << 32) | (unsigned)i;
    bitonic_u64(s, i, 64);
    int src = (int)(unsigned)(s[i] & 0xffffffffull);
    sel_ids[bl * 64 + i] = ids_in[bl * 64 + src];
    sel_mk [bl * 64 + i] = mk_in [bl * 64 + src];
}

// ---------------- E table v2: tiled gather-GEMM ----------------
// Block (l, b): E[b, ts, l*64+s] = qw[b, ts+1] . Ktab[sel_ids[b,l,s]]
// Tile 64 (s) x 64 (ts, only 49 valid), BK=16, 4x4 f64 acc per thread.
__global__ __launch_bounds__(256) void etab2(
    const float* __restrict__ qw, const float* __restrict__ Ktab,
    const int* __restrict__ sel_ids, float* __restrict__ E)
{
    const int l = blockIdx.x;   // 0..49
    const int b = blockIdx.y;   // 0..15
    __shared__ float Ks[16][64];
    __shared__ float Qs[16][68];
    __shared__ int ids[64];
    const int t  = threadIdx.x;
    const int tx = t & 15, ty = t >> 4;
    if (t < 64) ids[t] = sel_ids[(b * kL + l) * 64 + t];
    __syncthreads();

    const int rA = t >> 2;          // 0..63 candidate row / ts col
    const int kA = (t & 3) * 4;     // 0,4,8,12
    const float* aptr = Ktab + (long long)ids[rA] * 256 + kA;
    const float* qbase = qw + ((long long)b * kL + 1) * 256;   // row ts -> + ts*256
    const bool tsok = rA < 49;

    double acc[4][4];
    #pragma unroll
    for (int i = 0; i < 4; ++i)
        #pragma unroll
        for (int j = 0; j < 4; ++j) acc[i][j] = 0.0;

    for (int k0 = 0; k0 < 256; k0 += 16) {
        float4 av = *(const float4*)(aptr + k0);
        float4 bv = make_float4(0.f, 0.f, 0.f, 0.f);
        if (tsok) bv = *(const float4*)(qbase + (long long)rA * 256 + k0 + kA);
        __syncthreads();
        Ks[kA + 0][rA] = av.x; Ks[kA + 1][rA] = av.y;
        Ks[kA + 2][rA] = av.z; Ks[kA + 3][rA] = av.w;
        Qs[kA + 0][rA] = bv.x; Qs[kA + 1][rA] = bv.y;
        Qs[kA + 2][rA] = bv.z; Qs[kA + 3][rA] = bv.w;
        __syncthreads();
        #pragma unroll
        for (int k = 0; k < 16; ++k) {
            float a[4], q[4];
            *(float4*)&a[0] = *(const float4*)&Ks[k][tx * 4];
            *(float4*)&q[0] = *(const float4*)&Qs[k][ty * 4];
            #pragma unroll
            for (int i = 0; i < 4; ++i)
                #pragma unroll
                for (int j = 0; j < 4; ++j)
                    acc[i][j] += (double)a[i] * (double)q[j];
        }
    }
    #pragma unroll
    for (int j = 0; j < 4; ++j) {
        int ts = ty * 4 + j;
        if (ts >= 49) continue;
        #pragma unroll
        for (int i = 0; i < 4; ++i) {
            int s = tx * 4 + i;
            E[((long long)b * 49 + ts) * 3200 + l * 64 + s] = (float)acc[i][j];
        }
    }
}

// ---------------- sequential memory recurrence (one block per batch) ----------------
__global__ __launch_bounds__(128) void recur(
    const float* __restrict__ E, const int* __restrict__ sel_ids,
    const int* __restrict__ sel_mk, const int* __restrict__ lengths,
    int* __restrict__ memf, float* __restrict__ dout_mem)
{
    int b = blockIdx.x;
    int t = threadIdx.x;
    __shared__ int cid[64], cmk[64], ccd[64];
    __shared__ int fid[128], fmk[128], fcd[128];
    __shared__ unsigned long long sk[128];
    if (t < 64) {
        cid[t] = sel_ids[(b * kL) * 64 + t];
        cmk[t] = sel_mk [(b * kL) * 64 + t];
        ccd[t] = t;                       // candidate index of visit 0
    }
    __syncthreads();
    int tlast = lengths[b] - 2;           // in [0,48]
    for (int ts = 0; ts <= tlast; ++ts) {
        int id, mk, cd;
        if (t < 64) { id = cid[t]; mk = cmk[t]; cd = ccd[t]; }
        else {
            int j = t - 64;
            id = sel_ids[(b * kL + ts + 1) * 64 + j];
            mk = sel_mk [(b * kL + ts + 1) * 64 + j];
            cd = (ts + 1) * 64 + j;
        }
        float key = mk ? E[((long long)b * 49 + ts) * 3200 + cd] : NEG_HUGE;
        fid[t] = id; fmk[t] = mk; fcd[t] = cd;
        sk[t] = ((unsigned long long)(~f2sort(key)) << 32) | (unsigned)t;
        bitonic_u64(sk, t, 128);
        if (t < 64) {
            int src = (int)(unsigned)(sk[t] & 0xffffffffull);
            cid[t] = fid[src]; cmk[t] = fmk[src]; ccd[t] = fcd[src];
        }
        __syncthreads();
    }
    if (t < 64) {
        int v = cid[t];
        memf[b * 64 + t] = v;
        dout_mem[b * 64 + t] = (float)v;  // output 1 (ids as f32)
    }
}

// ---------------- final pooling + output head ----------------
__global__ __launch_bounds__(256) void head_k(
    const float* __restrict__ tva, const int* __restrict__ lengths,
    const float* __restrict__ Tmem, const float* __restrict__ out_w,
    const float* __restrict__ out_b, float* __restrict__ dout)
{
    int b = blockIdx.x, d = threadIdx.x;
    int len = lengths[b];
    float vf = NEG_HUGE;
    for (int l = 0; l < len; ++l) vf = fmaxf(vf, tva[((long long)b * kL + l) * 256 + d]);
    float mv = NEG_HUGE;
    for (int m = 0; m < 64; ++m) mv = fmaxf(mv, Tmem[((long long)b * 64 + m) * 256 + d]);
    double p0 = (double)vf * out_w[d * 2 + 0] + (double)mv * out_w[(256 + d) * 2 + 0];
    double p1 = (double)vf * out_w[d * 2 + 1] + (double)mv * out_w[(256 + d) * 2 + 1];
    __shared__ double r0[256], r1[256];
    r0[d] = p0; r1[d] = p1; __syncthreads();
    for (int off = 128; off; off >>= 1) {
        if (d < off) { r0[d] += r0[d + off]; r1[d] += r1[d + off]; }
        __syncthreads();
    }
    if (d == 0) {
        dout[b * 2 + 0] = (float)(r0[0] + out_b[0]);
        dout[b * 2 + 1] = (float)(r1[0] + out_b[1]);
    }
}

// ---------------- host orchestration ----------------
extern "C" void kernel_launch(void* const* d_in, const int* in_sizes, int n_in,
                              void* d_out, int out_size, void* d_ws, size_t ws_size,
                              hipStream_t stream)
{
    const float* v_all  = (const float*)d_in[0];
    const float* tva    = (const float*)d_in[1];
    const float* emb    = (const float*)d_in[2];
    const float* bt_w1  = (const float*)d_in[3];
    const float* bt_b1  = (const float*)d_in[4];
    const float* bt_w2  = (const float*)d_in[5];
    const float* bt_b2  = (const float*)d_in[6];
    const float* bt_g   = (const float*)d_in[7];
    const float* bt_bb  = (const float*)d_in[8];
    const float* wq     = (const float*)d_in[9];
    const float* wk     = (const float*)d_in[10];
    const float* am_w1  = (const float*)d_in[11];
    const float* am_b1  = (const float*)d_in[12];
    const float* am_w2  = (const float*)d_in[13];
    const float* out_w  = (const float*)d_in[14];
    const float* out_b  = (const float*)d_in[15];
    const int*   in_txt = (const int*)d_in[16];
    const int*   mk_txt = (const int*)d_in[17];
    const int*   lens   = (const int*)d_in[18];
    float* dout = (float*)d_out;

    // ---- workspace layout (floats) ----
    const size_t FT_TAB = (size_t)kNBLK * 256;          // 16.78M each
    const size_t FT_E   = (size_t)16 * 49 * 3200;       // 2.51M
    const size_t FT_SM  = (size_t)800 * 256 * 3 + (size_t)800 * 64 * 3 + 1024 + 64;
    int CH = 32768;
    for (;;) {
        size_t yrows = (size_t)(CH > 1024 ? CH : 1024);
        size_t need = FT_TAB * 2 + FT_E + (size_t)CH * 512 + yrows * 256 + FT_SM + 64;
        if (need * 4 <= ws_size || CH == 1024) break;
        CH >>= 1;
    }
    size_t off = 0;
    float* W = (float*)d_ws;
    auto take = [&](size_t n) { float* p = W + off; off += (n + 3) & ~(size_t)3; return p; };
    float* Atab = take(FT_TAB);
    float* Ktab = take(FT_TAB);
    float* Ep   = take(FT_E);
    float* Hp   = take((size_t)CH * 512);
    float* Yp   = take((size_t)(CH > 1024 ? CH : 1024) * 256);
    float* qrP  = take((size_t)800 * 256);
    float* tvpP = take((size_t)800 * 256);
    float* qwP  = take((size_t)800 * 256);
    float* scP  = take((size_t)800 * 64);
    int*   selI = (int*)take((size_t)800 * 64);
    int*   selM = (int*)take((size_t)800 * 64);
    int*   memfP = (int*)take(1024);

    // 1) query = transformed_v_all + v_all
    add_vec<<<dim3((204800 + 255) / 256), dim3(256), 0, stream>>>(v_all, tva, qrP, 204800);

    // 2) tvp = tva @ am_w1[:256] + am_b1 ; qw = query @ wq
    gemm128_f32<<<dim3(7, 2), dim3(256), 0, stream>>>(
        tva, 256, nullptr, 0, am_w1, 256, tvpP, 256, 800, 256, 256, am_b1, 0);
    gemm128_f32<<<dim3(7, 2), dim3(256), 0, stream>>>(
        qrP, 256, nullptr, 0, wq, 256, qwP, 256, 800, 256, 256, nullptr, 0);

    // 3) per-ID tables in chunks: T (via H,Y), then A = T@am_w1[256:], K = T@wk
    int nch = kNBLK / CH;
    for (int c = 0; c < nch; ++c) {
        gemm128_f32<<<dim3(CH / 128, 4), dim3(256), 0, stream>>>(
            emb, 768, nullptr, c * CH, bt_w1, 512, Hp, 512, CH, 512, 768, bt_b1, 1);
        gemm128_f32<<<dim3(CH / 128, 2), dim3(256), 0, stream>>>(
            Hp, 512, nullptr, 0, bt_w2, 256, Yp, 256, CH, 256, 512, bt_b2, 0);
        ln256_inplace<<<dim3(CH), dim3(256), 0, stream>>>(Yp, bt_g, bt_bb, CH);
        gemm128_f32<<<dim3(CH / 128, 2), dim3(256), 0, stream>>>(
            Yp, 256, nullptr, 0, am_w1 + 256 * 256, 256, Atab + (size_t)c * CH * 256,
            256, CH, 256, 256, nullptr, 0);
        gemm128_f32<<<dim3(CH / 128, 2), dim3(256), 0, stream>>>(
            Yp, 256, nullptr, 0, wk, 256, Ktab + (size_t)c * CH * 256,
            256, CH, 256, 256, nullptr, 0);
    }

    // 4) phase-1 scores + stable full sort -> sel_ids / sel_mask
    p1score<<<dim3(800), dim3(256), 0, stream>>>(tvpP, Atab, am_w2, in_txt, scP);
    p1sort<<<dim3(800), dim3(64), 0, stream>>>(scP, in_txt, mk_txt, selI, selM);

    // 5) E table for all (b, t, candidate)
    etab2<<<dim3(50, 16), dim3(256), 0, stream>>>(qwP, Ktab, selI, Ep);

    // 6) sequential recurrence -> memory_final (writes output 1)
    recur<<<dim3(16), dim3(128), 0, stream>>>(Ep, selI, selM, lens, memfP, dout + 32);

    // 7) transform memory_final ids -> Tmem (reuse Hp/Yp)
    gemm128_f32<<<dim3(8, 4), dim3(256), 0, stream>>>(
        emb, 768, memfP, 0, bt_w1, 512, Hp, 512, 1024, 512, 768, bt_b1, 1);
    gemm128_f32<<<dim3(8, 2), dim3(256), 0, stream>>>(
        Hp, 512, nullptr, 0, bt_w2, 256, Yp, 256, 1024, 256, 512, bt_b2, 0);
    ln256_inplace<<<dim3(1024), dim3(256), 0, stream>>>(Yp, bt_g, bt_bb, 1024);

    // 8) pooling + output head (writes output 0)
    head_k<<<dim3(16), dim3(256), 0, stream>>>(tva, lens, Yp, out_w, out_b, dout);
}